// Round 6
// baseline (304.550 us; speedup 1.0000x reference)
//
#include <hip/hip_runtime.h>
#include <hip/hip_bf16.h>
#include <stdint.h>

#define N_NODES 100000
#define N_EDGES 640000
#define MPAD    100096   // multiple of 128, >= N_NODES
#define EDGE_BLOCKS ((N_EDGES + 255) / 256)          // 2500
#define CONV4_T     (N_NODES * 32)                   // float4 threads (128ch/4)
#define CONV4_BLOCKS ((CONV4_T + 255) / 256)         // 12500

typedef short  bf8_t  __attribute__((ext_vector_type(8)));   // 8 bf16 (4 VGPRs)
typedef float  f32x4  __attribute__((ext_vector_type(4)));

__device__ __forceinline__ unsigned f2bf(float f) {  // RNE f32 -> bf16 bits
  unsigned u = __builtin_bit_cast(unsigned, f);
  return ((u + 0x7fffu + ((u >> 16) & 1u)) >> 16) & 0xffffu;
}
__device__ __forceinline__ float bf2f(unsigned bits) {
  return __builtin_bit_cast(float, bits << 16);
}

// ---------------- CSR count ----------------
__global__ void k_count(const int* __restrict__ dst, int* __restrict__ cnt) {
  int e = blockIdx.x * blockDim.x + threadIdx.x;
  if (e < N_EDGES) atomicAdd(&cnt[dst[e]], 1);
}

__global__ void k_bsum(const int* __restrict__ cnt, int* __restrict__ bsum) {
  __shared__ int s[256];
  int base = blockIdx.x * 1024;
  int t = threadIdx.x;
  int v = 0;
  for (int j = 0; j < 4; ++j) {
    int i = base + j * 256 + t;
    if (i < N_NODES) v += cnt[i];
  }
  s[t] = v; __syncthreads();
  for (int o = 128; o > 0; o >>= 1) { if (t < o) s[t] += s[t + o]; __syncthreads(); }
  if (t == 0) bsum[blockIdx.x] = s[0];
}

// parallel exclusive scan of nb (<=128) block sums, one block of 128 threads
__global__ void k_scanb(int* __restrict__ bsum, int nb) {
  __shared__ int s[128];
  int t = threadIdx.x;
  int v = (t < nb) ? bsum[t] : 0;
  s[t] = v; __syncthreads();
  for (int o = 1; o < 128; o <<= 1) {
    int add = (t >= o) ? s[t - o] : 0;
    __syncthreads();
    s[t] += add;
    __syncthreads();
  }
  if (t < nb) bsum[t] = s[t] - v;   // exclusive
}

__global__ void k_scanchunk(const int* __restrict__ cnt, const int* __restrict__ bsum,
                            int* __restrict__ rowptr, float* __restrict__ inv,
                            int* __restrict__ cursor) {
  __shared__ int s[1024];
  int t = threadIdx.x;
  int i = blockIdx.x * 1024 + t;
  int v = (i < N_NODES) ? cnt[i] : 0;
  s[t] = v; __syncthreads();
  for (int o = 1; o < 1024; o <<= 1) {
    int add = (t >= o) ? s[t - o] : 0;
    __syncthreads();
    s[t] += add;
    __syncthreads();
  }
  int incl = s[t];
  int bofs = bsum[blockIdx.x];
  if (i < N_NODES) {
    rowptr[i] = bofs + incl - v;
    inv[i] = 1.0f / fmaxf((float)v, 1.0f);
    cursor[i] = 0;
  }
  if (i == N_NODES - 1) rowptr[N_NODES] = bofs + incl;
}

// ---------------- scatter + prep (x->bf16 self-half, weight swizzle) --------
// Bf[((kc*8+t)*64 + lane)*8 + j] = B[kc*32 + (lane>>4)*8 + j][t*16 + (lane&15)]
// where B[k][c] = (k<128) ? Wl[c][k] : Wr[c][k-128]
__global__ void k_scatter_prep(const int* __restrict__ src, const int* __restrict__ dst,
                               const int* __restrict__ rowptr, int* __restrict__ cursor,
                               int* __restrict__ esrc,
                               const float* __restrict__ x, unsigned* __restrict__ A1,
                               const float* __restrict__ Wl1, const float* __restrict__ Wr1,
                               unsigned short* __restrict__ Bf1,
                               const float* __restrict__ Wl2, const float* __restrict__ Wr2,
                               unsigned short* __restrict__ Bf2) {
  int bx = blockIdx.x;
  if (bx < EDGE_BLOCKS) {
    int e = bx * 256 + threadIdx.x;
    if (e < N_EDGES) {
      int d = dst[e];
      int p = atomicAdd(&cursor[d], 1);
      esrc[rowptr[d] + p] = src[e];
    }
    return;
  }
  if (bx < EDGE_BLOCKS + CONV4_BLOCKS) {
    int i = (bx - EDGE_BLOCKS) * 256 + threadIdx.x;   // float4 index
    if (i < CONV4_T) {
      int w = i >> 5, t = i & 31;                     // node, quad-of-channels
      float4 f = ((const float4*)x)[i];
      uint2 u;
      u.x = f2bf(f.x) | (f2bf(f.y) << 16);
      u.y = f2bf(f.z) | (f2bf(f.w) << 16);
      ((uint2*)A1)[(size_t)w * 64 + 32 + t] = u;      // self-half
    }
    return;
  }
  int gid = (bx - EDGE_BLOCKS - CONV4_BLOCKS) * 256 + threadIdx.x;
  if (gid >= 8192) return;
  int tid = gid & 4095;
  const float* Wl = (gid < 4096) ? Wl1 : Wl2;
  const float* Wr = (gid < 4096) ? Wr1 : Wr2;
  unsigned short* Bf = (gid < 4096) ? Bf1 : Bf2;
  int lane = tid & 63;
  int t  = (tid >> 6) & 7;
  int kc = tid >> 9;
  int c = lane & 15, q = lane >> 4;
  int col = t * 16 + c;
  for (int j = 0; j < 8; ++j) {
    int k = kc * 32 + q * 8 + j;
    float v = (k < 128) ? Wl[col * 128 + k] : Wr[col * 128 + (k - 128)];
    Bf[(size_t)tid * 8 + j] = (unsigned short)f2bf(v);
  }
}

// ---------------- mean aggregation: gather bf16 self-rows of A, write agg-half
// wave per node; uint2 (8B) per lane -> 32 lanes cover one 256B row, so each
// batch of 8 issues fetches 16 neighbor rows. Halves combined via shfl_xor(32).
__global__ __launch_bounds__(256) void k_agg(unsigned* __restrict__ A,
    const int* __restrict__ rowptr, const int* __restrict__ esrc,
    const float* __restrict__ inv) {
  int w = (blockIdx.x * blockDim.x + threadIdx.x) >> 6;  // node
  int lane = threadIdx.x & 63;
  if (w >= N_NODES) return;
  int b = rowptr[w], e = rowptr[w + 1];
  int deg = e - b;
  int myi = (lane < deg) ? esrc[b + lane] : 0;   // coalesced index preload
  int half = lane >> 5, l32 = lane & 31;
  const uint2* Av = (const uint2*)A;             // row stride 64 uint2; self at +32
  float ax = 0.f, ay = 0.f, az = 0.f, aw = 0.f;
  int n = (deg < 64) ? deg : 64;
  for (int j0 = 0; j0 < n; j0 += 16) {
    uint2 u[8];
#pragma unroll
    for (int jj = 0; jj < 8; ++jj) {
      int slot = j0 + jj * 2 + half;
      int s = __shfl(myi, slot);                 // 16 rows per latency window
      u[jj] = Av[(size_t)s * 64 + 32 + l32];
    }
#pragma unroll
    for (int jj = 0; jj < 8; ++jj) {
      if (j0 + jj * 2 + half < n) {
        ax += bf2f(u[jj].x & 0xffffu); ay += bf2f(u[jj].x >> 16);
        az += bf2f(u[jj].y & 0xffffu); aw += bf2f(u[jj].y >> 16);
      }
    }
  }
  for (int j = 64; j < deg; j += 2) {            // deg>64 tail (rare)
    int slot = j + half;
    int s = (slot < deg) ? esrc[b + slot] : 0;
    uint2 u = Av[(size_t)s * 64 + 32 + l32];
    if (slot < deg) {
      ax += bf2f(u.x & 0xffffu); ay += bf2f(u.x >> 16);
      az += bf2f(u.y & 0xffffu); aw += bf2f(u.y >> 16);
    }
  }
  ax += __shfl_xor(ax, 32, 64); ay += __shfl_xor(ay, 32, 64);
  az += __shfl_xor(az, 32, 64); aw += __shfl_xor(aw, 32, 64);
  float iv = inv[w];
  if (half == 0) {
    uint2 o;
    o.x = f2bf(ax * iv) | (f2bf(ay * iv) << 16);
    o.y = f2bf(az * iv) | (f2bf(aw * iv) << 16);
    ((uint2*)A)[(size_t)w * 64 + l32] = o;       // agg-half
  }
}

// ---------------- fused GEMM (M x 256 @ 256 x 128) + bias + L2norm (+relu) ---
// 256 thr / 4 waves / 128 rows per block. B staged once into 64KB LDS; K-loop
// is ds_read_b128 + MFMA. A-frags (16 x 16B) issued before staging to overlap.
// LAYER 1: bf16 -> A2 self-half (paired 4B stores). LAYER 2: fp32 -> d_out.
template<int LAYER>
__global__ __launch_bounds__(256) void k_gemm(const unsigned short* __restrict__ A,
    const unsigned short* __restrict__ Bf, const float* __restrict__ bias,
    void* __restrict__ outp) {
  __shared__ unsigned short Bs[32768];   // 64 KB
  int wid = threadIdx.x >> 6;
  int lane = threadIdx.x & 63;
  int c = lane & 15, q = lane >> 4;
  int m0 = blockIdx.x * 128 + wid * 32;   // this wave: rows [m0, m0+32)

  bf8_t a0[8], a1[8];
#pragma unroll
  for (int kc = 0; kc < 8; ++kc) {       // 16 independent global loads in flight
    a0[kc] = *(const bf8_t*)(A + (size_t)(m0 + c) * 256 + kc * 32 + q * 8);
    a1[kc] = *(const bf8_t*)(A + (size_t)(m0 + 16 + c) * 256 + kc * 32 + q * 8);
  }
  // stage B -> LDS (4096 x 16B)
#pragma unroll
  for (int i = 0; i < 16; ++i)
    ((bf8_t*)Bs)[i * 256 + threadIdx.x] = ((const bf8_t*)Bf)[i * 256 + threadIdx.x];
  __syncthreads();

  f32x4 acc[2][8];
#pragma unroll
  for (int h = 0; h < 2; ++h)
#pragma unroll
    for (int t = 0; t < 8; ++t) acc[h][t] = (f32x4){0.f, 0.f, 0.f, 0.f};
  const bf8_t* Bv = (const bf8_t*)Bs;
#pragma unroll
  for (int kc = 0; kc < 8; ++kc) {
#pragma unroll
    for (int t = 0; t < 8; ++t) {
      bf8_t b = Bv[(kc * 8 + t) * 64 + lane];
      acc[0][t] = __builtin_amdgcn_mfma_f32_16x16x32_bf16(a0[kc], b, acc[0][t], 0, 0, 0);
      acc[1][t] = __builtin_amdgcn_mfma_f32_16x16x32_bf16(a1[kc], b, acc[1][t], 0, 0, 0);
    }
  }
  float bcol[8];
#pragma unroll
  for (int t = 0; t < 8; ++t) bcol[t] = bias[t * 16 + c];
#pragma unroll
  for (int h = 0; h < 2; ++h) {
#pragma unroll
    for (int r = 0; r < 4; ++r) {
      float ss = 0.f;
#pragma unroll
      for (int t = 0; t < 8; ++t) {
        float v = acc[h][t][r] + bcol[t];
        acc[h][t][r] = v;
        ss += v * v;
      }
#pragma unroll
      for (int m = 1; m < 16; m <<= 1) ss += __shfl_xor(ss, m, 64);
      float invn = 1.0f / fmaxf(sqrtf(ss), 1e-12f);
      int row = m0 + h * 16 + q * 4 + r;
      if (LAYER == 1) {
        unsigned* o32 = (unsigned*)outp;  // A2 base (bf16 pairs), self-half
#pragma unroll
        for (int t = 0; t < 8; ++t) {
          float v = fmaxf(acc[h][t][r] * invn, 0.f);
          float vp = __shfl_xor(v, 1, 64);         // partner col (c^1)
          if (row < N_NODES && !(c & 1))
            o32[(size_t)row * 128 + 64 + t * 8 + (c >> 1)] = f2bf(v) | (f2bf(vp) << 16);
        }
      } else {
        float* o = (float*)outp;
        if (row < N_NODES) {
#pragma unroll
          for (int t = 0; t < 8; ++t)
            o[(size_t)row * 128 + t * 16 + c] = acc[h][t][r] * invn;
        }
      }
    }
  }
}

extern "C" void kernel_launch(void* const* d_in, const int* in_sizes, int n_in,
                              void* d_out, int out_size, void* d_ws, size_t ws_size,
                              hipStream_t stream) {
  const float* x   = (const float*)d_in[0];
  const int*   ei  = (const int*)d_in[1];
  const int*   src = ei;
  const int*   dst = ei + N_EDGES;
  const float* Wl1 = (const float*)d_in[2];
  const float* bl1 = (const float*)d_in[3];
  const float* Wr1 = (const float*)d_in[4];
  const float* Wl2 = (const float*)d_in[5];
  const float* bl2 = (const float*)d_in[6];
  const float* Wr2 = (const float*)d_in[7];

  char* ws = (char*)d_ws;
  size_t off = 0;
  auto alloc = [&](size_t bytes) -> void* {
    void* p = ws + off;
    off += (bytes + 255) & ~(size_t)255;
    return p;
  };
  // A1/A2: [MPAD, 256] bf16; cols 0..127 = agg, cols 128..255 = self features
  unsigned short* A1  = (unsigned short*)alloc((size_t)MPAD * 256 * 2);
  unsigned short* A2  = (unsigned short*)alloc((size_t)MPAD * 256 * 2);
  unsigned short* Bf1 = (unsigned short*)alloc(65536);
  unsigned short* Bf2 = (unsigned short*)alloc(65536);
  int*   esrc   = (int*)alloc((size_t)N_EDGES * 4);
  int*   rowptr = (int*)alloc((size_t)(N_NODES + 1) * 4);
  int*   cnt    = (int*)alloc((size_t)N_NODES * 4);
  int*   cursor = (int*)alloc((size_t)N_NODES * 4);
  float* inv    = (float*)alloc((size_t)N_NODES * 4);
  int*   bsum   = (int*)alloc(1024);

  hipMemsetAsync(cnt, 0, (size_t)N_NODES * 4, stream);

  const int NB = (N_NODES + 1023) / 1024;  // 98
  k_count      <<<EDGE_BLOCKS, 256, 0, stream>>>(dst, cnt);
  k_bsum       <<<NB, 256, 0, stream>>>(cnt, bsum);
  k_scanb      <<<1, 128, 0, stream>>>(bsum, NB);
  k_scanchunk  <<<NB, 1024, 0, stream>>>(cnt, bsum, rowptr, inv, cursor);
  k_scatter_prep<<<EDGE_BLOCKS + CONV4_BLOCKS + 32, 256, 0, stream>>>(
                 src, dst, rowptr, cursor, esrc,
                 x, (unsigned*)A1, Wl1, Wr1, Bf1, Wl2, Wr2, Bf2);

  // layer 1: A1.agg = mean-gather(A1.self); A2.self = relu(l2norm(A1 @ Bf1 + bl1))
  k_agg    <<<(N_NODES * 64 + 255) / 256, 256, 0, stream>>>((unsigned*)A1, rowptr, esrc, inv);
  k_gemm<1><<<MPAD / 128, 256, 0, stream>>>(A1, Bf1, bl1, A2);
  // layer 2: A2.agg = mean-gather(A2.self); d_out = l2norm(A2 @ Bf2 + bl2)
  k_agg    <<<(N_NODES * 64 + 255) / 256, 256, 0, stream>>>((unsigned*)A2, rowptr, esrc, inv);
  k_gemm<2><<<MPAD / 128, 256, 0, stream>>>(A2, Bf2, bl2, d_out);
}

// Round 7
// 293.434 us; speedup vs baseline: 1.0379x; 1.0379x over previous
//
#include <hip/hip_runtime.h>
#include <hip/hip_bf16.h>
#include <stdint.h>

#define N_NODES 100000
#define N_EDGES 640000
#define MPAD    100096   // multiple of 128, >= N_NODES
#define CNT4_BLOCKS (N_EDGES / 1024)                 // 625 (4 edges/thread)
#define CONV4_T     (N_NODES * 32)                   // float4 threads (128ch/4)
#define CONV4_BLOCKS ((CONV4_T + 255) / 256)         // 12500

typedef short  bf8_t  __attribute__((ext_vector_type(8)));   // 8 bf16 (4 VGPRs)
typedef float  f32x4  __attribute__((ext_vector_type(4)));

__device__ __forceinline__ unsigned f2bf(float f) {  // RNE f32 -> bf16 bits
  unsigned u = __builtin_bit_cast(unsigned, f);
  return ((u + 0x7fffu + ((u >> 16) & 1u)) >> 16) & 0xffffu;
}
__device__ __forceinline__ float bf2f(unsigned bits) {
  return __builtin_bit_cast(float, bits << 16);
}

// ---------------- CSR count (4 edges/thread) + conv + weight swizzle --------
// Bf[((kc*8+t)*64 + lane)*8 + j] = B[kc*32 + (lane>>4)*8 + j][t*16 + (lane&15)]
// where B[k][c] = (k<128) ? Wl[c][k] : Wr[c][k-128]
__global__ void k_count_conv(const int* __restrict__ dst, int* __restrict__ cnt,
                             const float* __restrict__ x, unsigned* __restrict__ A1,
                             const float* __restrict__ Wl1, const float* __restrict__ Wr1,
                             unsigned short* __restrict__ Bf1,
                             const float* __restrict__ Wl2, const float* __restrict__ Wr2,
                             unsigned short* __restrict__ Bf2) {
  int bx = blockIdx.x;
  if (bx < CNT4_BLOCKS) {
    int base = bx * 1024 + threadIdx.x;
    int d0 = dst[base], d1 = dst[base + 256], d2 = dst[base + 512], d3 = dst[base + 768];
    atomicAdd(&cnt[d0], 1);   // 4 independent atomic chains per lane
    atomicAdd(&cnt[d1], 1);
    atomicAdd(&cnt[d2], 1);
    atomicAdd(&cnt[d3], 1);
    return;
  }
  if (bx < CNT4_BLOCKS + CONV4_BLOCKS) {
    int i = (bx - CNT4_BLOCKS) * 256 + threadIdx.x;   // float4 index
    if (i < CONV4_T) {
      int w = i >> 5, t = i & 31;
      float4 f = ((const float4*)x)[i];
      uint2 u;
      u.x = f2bf(f.x) | (f2bf(f.y) << 16);
      u.y = f2bf(f.z) | (f2bf(f.w) << 16);
      ((uint2*)A1)[(size_t)w * 64 + 32 + t] = u;      // self-half
    }
    return;
  }
  int gid = (bx - CNT4_BLOCKS - CONV4_BLOCKS) * 256 + threadIdx.x;
  if (gid >= 8192) return;
  int tid = gid & 4095;
  const float* Wl = (gid < 4096) ? Wl1 : Wl2;
  const float* Wr = (gid < 4096) ? Wr1 : Wr2;
  unsigned short* Bf = (gid < 4096) ? Bf1 : Bf2;
  int lane = tid & 63;
  int t  = (tid >> 6) & 7;
  int kc = tid >> 9;
  int c = lane & 15, q = lane >> 4;
  int col = t * 16 + c;
  for (int j = 0; j < 8; ++j) {
    int k = kc * 32 + q * 8 + j;
    float v = (k < 128) ? Wl[col * 128 + k] : Wr[col * 128 + (k - 128)];
    Bf[(size_t)tid * 8 + j] = (unsigned short)f2bf(v);
  }
}

__global__ void k_bsum(const int* __restrict__ cnt, int* __restrict__ bsum) {
  __shared__ int s[256];
  int base = blockIdx.x * 1024;
  int t = threadIdx.x;
  int v = 0;
  for (int j = 0; j < 4; ++j) {
    int i = base + j * 256 + t;
    if (i < N_NODES) v += cnt[i];
  }
  s[t] = v; __syncthreads();
  for (int o = 128; o > 0; o >>= 1) { if (t < o) s[t] += s[t + o]; __syncthreads(); }
  if (t == 0) bsum[blockIdx.x] = s[0];
}

// parallel exclusive scan of nb (<=128) block sums, one block of 128 threads
__global__ void k_scanb(int* __restrict__ bsum, int nb) {
  __shared__ int s[128];
  int t = threadIdx.x;
  int v = (t < nb) ? bsum[t] : 0;
  s[t] = v; __syncthreads();
  for (int o = 1; o < 128; o <<= 1) {
    int add = (t >= o) ? s[t - o] : 0;
    __syncthreads();
    s[t] += add;
    __syncthreads();
  }
  if (t < nb) bsum[t] = s[t] - v;   // exclusive
}

__global__ void k_scanchunk(const int* __restrict__ cnt, const int* __restrict__ bsum,
                            int* __restrict__ rowptr, float* __restrict__ inv,
                            int* __restrict__ cursor) {
  __shared__ int s[1024];
  int t = threadIdx.x;
  int i = blockIdx.x * 1024 + t;
  int v = (i < N_NODES) ? cnt[i] : 0;
  s[t] = v; __syncthreads();
  for (int o = 1; o < 1024; o <<= 1) {
    int add = (t >= o) ? s[t - o] : 0;
    __syncthreads();
    s[t] += add;
    __syncthreads();
  }
  int incl = s[t];
  int bofs = bsum[blockIdx.x];
  if (i < N_NODES) {
    int start = bofs + incl - v;
    rowptr[i] = start;
    inv[i] = 1.0f / fmaxf((float)v, 1.0f);
    cursor[i] = start;            // absolute-slot seed: scatter needs no rowptr read
  }
  if (i == N_NODES - 1) rowptr[N_NODES] = bofs + incl;
}

// ---------------- scatter: 4 edges/thread, absolute-slot cursor -------------
__global__ void k_scatter(const int* __restrict__ src, const int* __restrict__ dst,
                          int* __restrict__ cursor, int* __restrict__ esrc) {
  int base = blockIdx.x * 1024 + threadIdx.x;
  int d0 = dst[base],       d1 = dst[base + 256];
  int d2 = dst[base + 512], d3 = dst[base + 768];
  int s0 = src[base],       s1 = src[base + 256];
  int s2 = src[base + 512], s3 = src[base + 768];
  int p0 = atomicAdd(&cursor[d0], 1);   // 4 independent chains
  int p1 = atomicAdd(&cursor[d1], 1);
  int p2 = atomicAdd(&cursor[d2], 1);
  int p3 = atomicAdd(&cursor[d3], 1);
  esrc[p0] = s0; esrc[p1] = s1; esrc[p2] = s2; esrc[p3] = s3;
}

// ---------------- mean aggregation (R5-proven): 8 x 4B-lane row gathers -----
__global__ __launch_bounds__(256) void k_agg(unsigned* __restrict__ A,
    const int* __restrict__ rowptr, const int* __restrict__ esrc,
    const float* __restrict__ inv) {
  int w = (blockIdx.x * blockDim.x + threadIdx.x) >> 6;  // node
  int lane = threadIdx.x & 63;
  if (w >= N_NODES) return;
  int b = rowptr[w], e = rowptr[w + 1];
  int deg = e - b;
  int myi = (lane < deg) ? esrc[b + lane] : 0;   // coalesced index preload
  float ax = 0.f, ay = 0.f;
  int n = (deg < 64) ? deg : 64;
  for (int j0 = 0; j0 < n; j0 += 8) {
    unsigned u[8];
#pragma unroll
    for (int j = 0; j < 8; ++j) {
      int s = __shfl(myi, j0 + j);                 // uniform lane -> sgpr addr
      u[j] = A[(size_t)s * 128 + 64 + lane];       // 8 independent 256B gathers
    }
#pragma unroll
    for (int j = 0; j < 8; ++j) {
      if (j0 + j < n) { ax += bf2f(u[j] & 0xffffu); ay += bf2f(u[j] >> 16); }
    }
  }
  for (int j = b + 64; j < e; ++j) {               // deg>64 tail (rare)
    int s = esrc[j];
    unsigned u = A[(size_t)s * 128 + 64 + lane];
    ax += bf2f(u & 0xffffu); ay += bf2f(u >> 16);
  }
  float iv = inv[w];
  A[(size_t)w * 128 + lane] = f2bf(ax * iv) | (f2bf(ay * iv) << 16);  // agg-half
}

// ---------------- fused GEMM (M x 256 @ 256 x 128) + bias + L2norm (+relu) ---
// 256 thr / 4 waves / 128 rows per block. B staged once into 64KB LDS; K-loop
// is ds_read_b128 + MFMA. A-frags (16 x 16B) issued before staging to overlap.
// LAYER 1: bf16 -> A2 self-half (paired 4B stores). LAYER 2: fp32 -> d_out.
template<int LAYER>
__global__ __launch_bounds__(256) void k_gemm(const unsigned short* __restrict__ A,
    const unsigned short* __restrict__ Bf, const float* __restrict__ bias,
    void* __restrict__ outp) {
  __shared__ unsigned short Bs[32768];   // 64 KB
  int wid = threadIdx.x >> 6;
  int lane = threadIdx.x & 63;
  int c = lane & 15, q = lane >> 4;
  int m0 = blockIdx.x * 128 + wid * 32;   // this wave: rows [m0, m0+32)

  bf8_t a0[8], a1[8];
#pragma unroll
  for (int kc = 0; kc < 8; ++kc) {       // 16 independent global loads in flight
    a0[kc] = *(const bf8_t*)(A + (size_t)(m0 + c) * 256 + kc * 32 + q * 8);
    a1[kc] = *(const bf8_t*)(A + (size_t)(m0 + 16 + c) * 256 + kc * 32 + q * 8);
  }
  // stage B -> LDS (4096 x 16B)
#pragma unroll
  for (int i = 0; i < 16; ++i)
    ((bf8_t*)Bs)[i * 256 + threadIdx.x] = ((const bf8_t*)Bf)[i * 256 + threadIdx.x];
  __syncthreads();

  f32x4 acc[2][8];
#pragma unroll
  for (int h = 0; h < 2; ++h)
#pragma unroll
    for (int t = 0; t < 8; ++t) acc[h][t] = (f32x4){0.f, 0.f, 0.f, 0.f};
  const bf8_t* Bv = (const bf8_t*)Bs;
#pragma unroll
  for (int kc = 0; kc < 8; ++kc) {
#pragma unroll
    for (int t = 0; t < 8; ++t) {
      bf8_t b = Bv[(kc * 8 + t) * 64 + lane];
      acc[0][t] = __builtin_amdgcn_mfma_f32_16x16x32_bf16(a0[kc], b, acc[0][t], 0, 0, 0);
      acc[1][t] = __builtin_amdgcn_mfma_f32_16x16x32_bf16(a1[kc], b, acc[1][t], 0, 0, 0);
    }
  }
  float bcol[8];
#pragma unroll
  for (int t = 0; t < 8; ++t) bcol[t] = bias[t * 16 + c];
#pragma unroll
  for (int h = 0; h < 2; ++h) {
#pragma unroll
    for (int r = 0; r < 4; ++r) {
      float ss = 0.f;
#pragma unroll
      for (int t = 0; t < 8; ++t) {
        float v = acc[h][t][r] + bcol[t];
        acc[h][t][r] = v;
        ss += v * v;
      }
#pragma unroll
      for (int m = 1; m < 16; m <<= 1) ss += __shfl_xor(ss, m, 64);
      float invn = 1.0f / fmaxf(sqrtf(ss), 1e-12f);
      int row = m0 + h * 16 + q * 4 + r;
      if (LAYER == 1) {
        unsigned* o32 = (unsigned*)outp;  // A2 base (bf16 pairs), self-half
#pragma unroll
        for (int t = 0; t < 8; ++t) {
          float v = fmaxf(acc[h][t][r] * invn, 0.f);
          float vp = __shfl_xor(v, 1, 64);         // partner col (c^1)
          if (row < N_NODES && !(c & 1))
            o32[(size_t)row * 128 + 64 + t * 8 + (c >> 1)] = f2bf(v) | (f2bf(vp) << 16);
        }
      } else {
        float* o = (float*)outp;
        if (row < N_NODES) {
#pragma unroll
          for (int t = 0; t < 8; ++t)
            o[(size_t)row * 128 + t * 16 + c] = acc[h][t][r] * invn;
        }
      }
    }
  }
}

extern "C" void kernel_launch(void* const* d_in, const int* in_sizes, int n_in,
                              void* d_out, int out_size, void* d_ws, size_t ws_size,
                              hipStream_t stream) {
  const float* x   = (const float*)d_in[0];
  const int*   ei  = (const int*)d_in[1];
  const int*   src = ei;
  const int*   dst = ei + N_EDGES;
  const float* Wl1 = (const float*)d_in[2];
  const float* bl1 = (const float*)d_in[3];
  const float* Wr1 = (const float*)d_in[4];
  const float* Wl2 = (const float*)d_in[5];
  const float* bl2 = (const float*)d_in[6];
  const float* Wr2 = (const float*)d_in[7];

  char* ws = (char*)d_ws;
  size_t off = 0;
  auto alloc = [&](size_t bytes) -> void* {
    void* p = ws + off;
    off += (bytes + 255) & ~(size_t)255;
    return p;
  };
  // A1/A2: [MPAD, 256] bf16; cols 0..127 = agg, cols 128..255 = self features
  unsigned short* A1  = (unsigned short*)alloc((size_t)MPAD * 256 * 2);
  unsigned short* A2  = (unsigned short*)alloc((size_t)MPAD * 256 * 2);
  unsigned short* Bf1 = (unsigned short*)alloc(65536);
  unsigned short* Bf2 = (unsigned short*)alloc(65536);
  int*   esrc   = (int*)alloc((size_t)N_EDGES * 4);
  int*   rowptr = (int*)alloc((size_t)(N_NODES + 1) * 4);
  int*   cnt    = (int*)alloc((size_t)N_NODES * 4);
  int*   cursor = (int*)alloc((size_t)N_NODES * 4);
  float* inv    = (float*)alloc((size_t)N_NODES * 4);
  int*   bsum   = (int*)alloc(1024);

  hipMemsetAsync(cnt, 0, (size_t)N_NODES * 4, stream);

  const int NB = (N_NODES + 1023) / 1024;  // 98
  k_count_conv<<<CNT4_BLOCKS + CONV4_BLOCKS + 32, 256, 0, stream>>>(
                 dst, cnt, x, (unsigned*)A1, Wl1, Wr1, Bf1, Wl2, Wr2, Bf2);
  k_bsum      <<<NB, 256, 0, stream>>>(cnt, bsum);
  k_scanb     <<<1, 128, 0, stream>>>(bsum, NB);
  k_scanchunk <<<NB, 1024, 0, stream>>>(cnt, bsum, rowptr, inv, cursor);
  k_scatter   <<<CNT4_BLOCKS, 256, 0, stream>>>(src, dst, cursor, esrc);

  // layer 1: A1.agg = mean-gather(A1.self); A2.self = relu(l2norm(A1 @ Bf1 + bl1))
  k_agg    <<<(N_NODES * 64 + 255) / 256, 256, 0, stream>>>((unsigned*)A1, rowptr, esrc, inv);
  k_gemm<1><<<MPAD / 128, 256, 0, stream>>>(A1, Bf1, bl1, A2);
  // layer 2: A2.agg = mean-gather(A2.self); d_out = l2norm(A2 @ Bf2 + bl2)
  k_agg    <<<(N_NODES * 64 + 255) / 256, 256, 0, stream>>>((unsigned*)A2, rowptr, esrc, inv);
  k_gemm<2><<<MPAD / 128, 256, 0, stream>>>(A2, Bf2, bl2, d_out);
}